// Round 3
// baseline (782.532 us; speedup 1.0000x reference)
//
#include <hip/hip_runtime.h>
#include <hip/hip_bf16.h>
#include <cstdint>
#include <cstddef>

// Problem constants
#define K_DIM   4096          // INF
#define N_DIM   11008         // OUTF
#define M_DIM   4096          // 2*2048
#define GROUPS  32
#define QROWS   512           // INF*4/32

typedef __bf16 bf16x8 __attribute__((ext_vector_type(8)));
typedef float  f32x4  __attribute__((ext_vector_type(4)));

// ---------------------------------------------------------------------------
// async 16B global -> LDS (wave-uniform LDS base + lane*16 semantics)
// ---------------------------------------------------------------------------
__device__ __forceinline__ void async16(const void* g, void* lds) {
    __builtin_amdgcn_global_load_lds(
        (const __attribute__((address_space(1))) uint32_t*)g,
        (__attribute__((address_space(3))) uint32_t*)lds,
        16, 0, 0);
}

// ---------------------------------------------------------------------------
// Kernel 1 (merged prep): dequant 4-bit -> Wt bf16 (N x K)  +  x fp32 -> bf16.
// Blocks [0, 2752): dequant tile 64n x 32 qrows, transpose via padded LDS.
// Blocks [2752, 4800): x conversion, grid-stride 4 chunks of 2048 elems.
// ---------------------------------------------------------------------------
#define DQ_NN     64
#define DQ_KK     32
#define DQ_ROW    264   // 256 k-elements + 8 pad
#define DQ_BLOCKS 2752  // 172 * 16
#define XC_BLOCKS 2048  // (M*K)/(4*256*8)

__global__ __launch_bounds__(256) void prep_kernel(
        const uint32_t* __restrict__ qw,
        const float* __restrict__ scales,
        const float* __restrict__ zeros,
        __bf16* __restrict__ Wt,
        const float* __restrict__ x,
        __bf16* __restrict__ xb) {
    __shared__ __align__(16) __bf16 T[DQ_NN * DQ_ROW];   // 33,792 B
    const int tid = threadIdx.x;

    if (blockIdx.x >= DQ_BLOCKS) {
        // ---- x fp32 -> bf16 ----
        const int blk = blockIdx.x - DQ_BLOCKS;
#pragma unroll
        for (int u = 0; u < 4; ++u) {
            const size_t i = (((size_t)blk * 4 + u) * 256 + tid) * 8;
            const float4* p = (const float4*)(x + i);
            float4 a = p[0];
            float4 b = p[1];
            bf16x8 o;
            o[0] = (__bf16)a.x; o[1] = (__bf16)a.y; o[2] = (__bf16)a.z; o[3] = (__bf16)a.w;
            o[4] = (__bf16)b.x; o[5] = (__bf16)b.y; o[6] = (__bf16)b.z; o[7] = (__bf16)b.w;
            *(bf16x8*)(xb + i) = o;
        }
        return;
    }

    // ---- dequant ----
    const int n0  = (blockIdx.x % 172) * DQ_NN;
    const int kk0 = (blockIdx.x / 172) * DQ_KK;

    // Phase 1: 64x32 = 2048 qwords, 8 per thread. Lanes consecutive in n.
#pragma unroll
    for (int it = 0; it < 8; ++it) {
        const int flat = it * 256 + tid;
        const int kk_l = flat >> 6;          // 0..31
        const int n_l  = flat & 63;          // 0..63
        const int kk   = kk0 + kk_l;
        const int n    = n0 + n_l;
        const uint32_t q = qw[(size_t)kk * N_DIM + n];
        const int g = kk >> 4;               // k-group = (kk*8)/128
        const float s = scales[(size_t)n * GROUPS + g];
        const float z = zeros[(size_t)n * GROUPS + g];
        bf16x8 w;
#pragma unroll
        for (int j = 0; j < 8; ++j) {
            float v = (float)((q >> (4 * j)) & 0xF) * s - z;
            w[j] = (__bf16)v;
        }
        *(bf16x8*)(&T[n_l * DQ_ROW + kk_l * 8]) = w;
    }
    __syncthreads();

    // Phase 2: write 64 rows x 256 k, 16B chunks, lanes consecutive in k.
#pragma unroll
    for (int it = 0; it < 8; ++it) {
        const int flat = it * 256 + tid;
        const int n_l    = flat >> 5;        // 0..63
        const int kchunk = flat & 31;        // 0..31
        bf16x8 v = *(const bf16x8*)(&T[n_l * DQ_ROW + kchunk * 8]);
        *(bf16x8*)(Wt + (size_t)(n0 + n_l) * K_DIM + (size_t)kk0 * 8 + kchunk * 8) = v;
    }
}

// ---------------------------------------------------------------------------
// Kernel 2: bf16 GEMM, C = A(M x K) * Bt(N x K)^T + bias, fp32 out.
// 128x128 tile, BK=64, 256 threads = 4 waves in 2x2, each wave 64x64
// (4x4 MFMA 16x16x32 bf16, 2 k-steps). global_load_lds width-16 staging
// with XOR bank swizzle: LDS[row][kc] = global[row][kc ^ (row&7)].
// 1-D grid with 16N x 32M supertile swizzle for L2 locality.
// ---------------------------------------------------------------------------
#define GN 86   // N_DIM/128
#define GM 32   // M_DIM/128
#define SN 16   // N-tiles per supertile column group
#define BK 64

__global__ __launch_bounds__(256, 4) void gemm_kernel(
        const __bf16* __restrict__ A,    // M x K row-major
        const __bf16* __restrict__ Bt,   // N x K row-major
        const float* __restrict__ bias,  // N
        float* __restrict__ C) {         // M x N row-major
    __shared__ __align__(16) __bf16 As[128 * BK];   // 16 KB
    __shared__ __align__(16) __bf16 Bs[128 * BK];   // 16 KB

    const int tid  = threadIdx.x;
    const int wave = tid >> 6;
    const int lane = tid & 63;
    const int wm   = wave >> 1;      // 0..1
    const int wn   = wave & 1;       // 0..1
    const int quad = lane >> 4;      // 0..3
    const int l16  = lane & 15;

    // --- supertile swizzle: consecutive blocks form a 16N x 32M rectangle ---
    const int bid = blockIdx.x;
    const int g   = bid >> 9;                 // / (GM*SN) = /512
    const int rem = bid & 511;
    int n_t, m_t;
    const int snw = (GN - g * SN) < SN ? (GN - g * SN) : SN;
    if (snw == SN) { n_t = g * SN + (rem & (SN - 1)); m_t = rem >> 4; }
    else           { n_t = g * SN + rem % snw;        m_t = rem / snw; }

    const int m0 = m_t * 128;
    const int n0 = n_t * 128;

    f32x4 acc[4][4] = {};

    // --- staging assignment --------------------------------------------------
    // 1024 16B-chunks per matrix per k-tile. Instr (wave,i), i=0..3 covers
    // chunks c = wave*256 + i*64 + lane. LDS dest = c*16 (linear).
    // chunk c -> row = c>>3, LDS k-chunk = c&7, GLOBAL k-chunk = (c&7)^(row&7).
    const __bf16* gA[4];
    const __bf16* gB[4];
    char* ldsA[4];
    char* ldsB[4];
#pragma unroll
    for (int i = 0; i < 4; ++i) {
        const int c   = wave * 256 + i * 64 + lane;
        const int row = c >> 3;
        const int gk  = (c & 7) ^ (row & 7);
        gA[i] = A  + (size_t)(m0 + row) * K_DIM + gk * 8;
        gB[i] = Bt + (size_t)(n0 + row) * K_DIM + gk * 8;
        ldsA[i] = (char*)As + (wave * 4 + i) * 1024;
        ldsB[i] = (char*)Bs + (wave * 4 + i) * 1024;
    }

    // fragment read bases; xor factor is per-lane constant (row & 7 == l16 & 7)
    const int xr = l16 & 7;
    const __bf16* la = As + (size_t)(wm * 64 + l16) * BK;
    const __bf16* lb = Bs + (size_t)(wn * 64 + l16) * BK;

    for (int kt = 0; kt < K_DIM / BK; ++kt) {
#pragma unroll
        for (int i = 0; i < 4; ++i) async16(gA[i], ldsA[i]);
#pragma unroll
        for (int i = 0; i < 4; ++i) async16(gB[i], ldsB[i]);
#pragma unroll
        for (int i = 0; i < 4; ++i) { gA[i] += BK; gB[i] += BK; }
        __syncthreads();                 // drain, loads visible

#pragma unroll
        for (int s = 0; s < 2; ++s) {
            bf16x8 af[4], bf[4];
#pragma unroll
            for (int i = 0; i < 4; ++i)
                af[i] = *(const bf16x8*)(la + i * 16 * BK + (((s * 4 + quad) ^ xr) * 8));
#pragma unroll
            for (int i = 0; i < 4; ++i)
                bf[i] = *(const bf16x8*)(lb + i * 16 * BK + (((s * 4 + quad) ^ xr) * 8));

#pragma unroll
            for (int i = 0; i < 4; ++i)
#pragma unroll
                for (int j = 0; j < 4; ++j)
                    acc[i][j] = __builtin_amdgcn_mfma_f32_16x16x32_bf16(
                        af[i], bf[j], acc[i][j], 0, 0, 0);
        }

        __syncthreads();                 // LDS reads done before next overwrite
    }

    // --- epilogue: C[m][n] = acc + bias[n] ----------------------------------
    // C/D layout: col = lane&15, row = quad*4 + reg
#pragma unroll
    for (int j = 0; j < 4; ++j) {
        const int n = n0 + wn * 64 + j * 16 + l16;
        const float bv = bias[n];
#pragma unroll
        for (int i = 0; i < 4; ++i) {
            const int mb = m0 + wm * 64 + i * 16 + quad * 4;
#pragma unroll
            for (int r = 0; r < 4; ++r) {
                C[(size_t)(mb + r) * N_DIM + n] = acc[i][j][r] + bv;
            }
        }
    }
}

// ---------------------------------------------------------------------------
extern "C" void kernel_launch(void* const* d_in, const int* in_sizes, int n_in,
                              void* d_out, int out_size, void* d_ws, size_t ws_size,
                              hipStream_t stream) {
    const float*    x      = (const float*)d_in[0];
    const uint32_t* qw     = (const uint32_t*)d_in[1];
    const float*    scales = (const float*)d_in[2];
    const float*    zeros  = (const float*)d_in[3];
    const float*    bias   = (const float*)d_in[4];
    float*          out    = (float*)d_out;

    // workspace layout: Wt (N*K bf16 = 90,177,536 B) | xb (M*K bf16 = 33,554,432 B)
    __bf16* Wt = (__bf16*)d_ws;
    __bf16* xb = (__bf16*)((char*)d_ws + (size_t)N_DIM * K_DIM * sizeof(__bf16));

    prep_kernel<<<DQ_BLOCKS + XC_BLOCKS, 256, 0, stream>>>(qw, scales, zeros, Wt, x, xb);

    gemm_kernel<<<GN * GM, 256, 0, stream>>>(xb, Wt, bias, out);
}